// Round 1
// baseline (140.107 us; speedup 1.0000x reference)
//
#include <hip/hip_runtime.h>
#include <hip/hip_bf16.h>

// Problem constants (from reference)
#define BB 8
#define CC 64
#define OO 64
#define HH 128
#define WW 128
#define HP 130   // padded
#define WP 130
#define KP 9

typedef __attribute__((ext_vector_type(8))) short bf16x8;
typedef __attribute__((ext_vector_type(4))) float f32x4;

static __device__ __forceinline__ float bf2f(unsigned short u) {
  return __uint_as_float(((unsigned)u) << 16);
}
static __device__ __forceinline__ unsigned short f2bf(float f) {
  // round-to-nearest-even bf16 (inputs are finite randoms; no NaN handling needed)
  unsigned u = __float_as_uint(f);
  unsigned r = u + 0x7fffu + ((u >> 16) & 1u);
  return (unsigned short)(r >> 16);
}

// ---------------------------------------------------------------------------
// Kernel 1: x [B][C][H][W] f32  ->  x_t [B][HP][WP][C] bf16, zero borders.
// Zero borders make OOB handling = clamp (pad rows/cols are exactly 0).
// ---------------------------------------------------------------------------
__global__ __launch_bounds__(256) void k_xpose(const float* __restrict__ x,
                                               unsigned short* __restrict__ xt) {
  __shared__ unsigned short tile[128][66];  // [w][c], pad to 66 to avoid bank conflicts
  int wg = blockIdx.x;            // B*H = 1024
  int h = wg & 127, b = wg >> 7;
  int t = threadIdx.x;
  int w = t & 127, chalf = t >> 7;
  const float* xp = x + ((size_t)(b * CC) * HH + h) * WW;  // x[b][0][h][0]
#pragma unroll 4
  for (int c2 = 0; c2 < 32; ++c2) {
    int c = c2 * 2 + chalf;
    float v = xp[(size_t)c * HH * WW + w];
    tile[w][c] = f2bf(v);
  }
  __syncthreads();
  int c = t & 63, w2 = t >> 6;
  unsigned short* xtb = xt + (size_t)b * HP * WP * CC;
#pragma unroll 4
  for (int w4 = 0; w4 < 32; ++w4) {
    int ww = w4 * 4 + w2;
    xtb[((size_t)(h + 1) * WP + (ww + 1)) * CC + c] = tile[ww][c];
  }
  // side borders (x = 0 and x = WP-1) for this row
  if (t < 128) {
    int xx = (t >= 64) ? (WP - 1) : 0;
    xtb[((size_t)(h + 1) * WP + xx) * CC + (t & 63)] = 0;
  }
  // top/bottom zero rows, once per b
  if (h == 0) {
    for (int i = t; i < 2 * WP * CC; i += 256) {
      int top = (i < WP * CC);
      int rem = top ? i : i - WP * CC;
      size_t y = top ? 0 : (HP - 1);
      xtb[y * WP * CC + rem] = 0;
    }
  }
}

// ---------------------------------------------------------------------------
// Kernel 2: weight [O][C][3][3] f32 -> bf16 fragments in MFMA B-operand order.
// flat = (((p*2+ks)*4+nf)*64 + lane)*8 + j ;  c = ks*32+(lane>>4)*8+j ; o = nf*16+(lane&15)
// ---------------------------------------------------------------------------
__global__ __launch_bounds__(256) void k_wfrag(const float* __restrict__ wsrc,
                                               unsigned short* __restrict__ wf) {
  int flat = blockIdx.x * 256 + threadIdx.x;  // < 36864 = 9<<12
  int j = flat & 7;
  int lane = (flat >> 3) & 63;
  int nf = (flat >> 9) & 3;
  int ks = (flat >> 11) & 1;
  int p = flat >> 12;
  int c = ks * 32 + ((lane >> 4) * 8) + j;
  int o = nf * 16 + (lane & 15);
  wf[flat] = f2bf(wsrc[(size_t)(o * CC + c) * KP + p]);
}

// ---------------------------------------------------------------------------
// Main kernel: one wg = (b, h, 64-wide w tile) x all 64 outputs.
// 4 waves; wave w owns pixels [16w, 16w+16). Barrier-free p-loop.
// ---------------------------------------------------------------------------
__global__ __launch_bounds__(256) void k_deform_main(const float* __restrict__ offset,
                                                     const float* __restrict__ bias,
                                                     const unsigned short* __restrict__ xt,
                                                     const unsigned short* __restrict__ wf,
                                                     float* __restrict__ out) {
  __shared__ __align__(16) char lds[17408];
  // layout: [0,9216)  coords: 4 waves * 144 entries * 16B
  //         [9216,17408) S tile: 64 px * 64 c * bf16 (XOR-swizzled rows)
  // epilogue reuses [0,16640) as S2: f32 [64][65]

  int wg = blockIdx.x;                 // 2048
  int tile = wg & 1, h = (wg >> 1) & 127, b = wg >> 8;
  int w0 = tile * 64;
  int t = threadIdx.x, wave = t >> 6, lane = t & 63;

  uint4* coords = reinterpret_cast<uint4*>(lds) + wave * 144;
  char* Sb = lds + 9216;

  // ---- phase 1: vectorized coordinate precompute (144 (p,px) pairs / wave) ----
#pragma unroll
  for (int it = 0; it < 3; ++it) {
    int pair = it * 64 + lane;
    if (pair < 144) {
      int p = pair >> 4, pxl = pair & 15;
      int px = wave * 16 + pxl;
      int w = w0 + px;
      const float* offp = offset + (((size_t)b * 18 + 2 * p) * HH + h) * WW + w;
      float offy = offp[0];
      float offx = offp[HH * WW];
      float cy = (float)(h + p / 3) + offy;   // (h+1) + (p/3 - 1) + offy
      float cx = (float)(w + p % 3) + offx;   // (w+1) + (p%3 - 1) + offx
      float y0f = floorf(cy), x0f = floorf(cx);
      float wy1 = cy - y0f, wx1 = cx - x0f;
      int iy0 = (int)y0f, ix0 = (int)x0f;
      int iy0c = min(max(iy0, 0), HP - 1);
      int iy1c = min(max(iy0 + 1, 0), HP - 1);
      int ix0c = min(max(ix0, 0), WP - 1);
      int ix1c = min(max(ix0 + 1, 0), WP - 1);
      uint4 e;
      e.x = (unsigned)(iy0c | (iy1c << 8) | (ix0c << 16) | (ix1c << 24));
      e.y = __float_as_uint(wy1);
      e.z = __float_as_uint(wx1);
      e.w = 0u;
      coords[pair] = e;  // wave-local; no barrier needed
    }
  }

  f32x4 acc[4];
#pragma unroll
  for (int nf = 0; nf < 4; ++nf) acc[nf] = (f32x4){0.f, 0.f, 0.f, 0.f};

  const unsigned short* xtb = xt + (size_t)b * HP * WP * CC;

  for (int p = 0; p < 9; ++p) {
    const uint4* cw = coords + p * 16;
    // ---- build S rows (this wave's 16 pixels), lane = channel ----
#pragma unroll 4
    for (int i = 0; i < 16; ++i) {
      uint4 e = cw[i];  // broadcast ds_read_b128
      int iy0 = e.x & 255, iy1 = (e.x >> 8) & 255;
      int ix0 = (e.x >> 16) & 255, ix1 = e.x >> 24;
      float wy1 = __uint_as_float(e.y), wx1 = __uint_as_float(e.z);
      int r0 = iy0 * WP, r1 = iy1 * WP;
      float v00 = bf2f(xtb[(r0 + ix0) * CC + lane]);
      float v01 = bf2f(xtb[(r0 + ix1) * CC + lane]);
      float v10 = bf2f(xtb[(r1 + ix0) * CC + lane]);
      float v11 = bf2f(xtb[(r1 + ix1) * CC + lane]);
      float top = fmaf(wx1, v01 - v00, v00);
      float bot = fmaf(wx1, v11 - v10, v10);
      float s = fmaf(wy1, bot - top, top);
      int px = wave * 16 + i;
      int ba = px * 128 + ((lane * 2) ^ ((px & 7) << 4));
      *reinterpret_cast<unsigned short*>(Sb + ba) = f2bf(s);
    }
    // ---- MFMA: K-slice of 64 (this p), 2 k-steps ----
#pragma unroll
    for (int ks = 0; ks < 2; ++ks) {
      int px = wave * 16 + (lane & 15);
      int c0b = ks * 64 + ((lane >> 4) * 16);  // byte offset of this lane's k-chunk
      int ba = px * 128 + (c0b ^ ((px & 7) << 4));
      bf16x8 a = *reinterpret_cast<const bf16x8*>(Sb + ba);
      const unsigned short* wfp = wf + (size_t)((p * 2 + ks) * 4) * 64 * 8;
#pragma unroll
      for (int nf = 0; nf < 4; ++nf) {
        bf16x8 bfrag = *reinterpret_cast<const bf16x8*>(wfp + ((nf * 64 + lane) * 8));
        acc[nf] = __builtin_amdgcn_mfma_f32_16x16x32_bf16(a, bfrag, acc[nf], 0, 0, 0);
      }
    }
  }

  // ---- epilogue: LDS transpose for coalesced NCHW stores ----
  __syncthreads();  // everyone done with coords/S before overwrite
  float* S2 = reinterpret_cast<float*>(lds);
#pragma unroll
  for (int nf = 0; nf < 4; ++nf) {
#pragma unroll
    for (int i2 = 0; i2 < 4; ++i2) {
      int px = wave * 16 + ((lane >> 4) * 4) + i2;  // C/D row
      int o = nf * 16 + (lane & 15);                // C/D col
      S2[px * 65 + o] = acc[nf][i2];
    }
  }
  __syncthreads();
  {
    int px = t & 63, o2 = t >> 6;
    float* op = out + (((size_t)b * OO) * HH + h) * WW + w0 + px;
#pragma unroll
    for (int o4 = 0; o4 < 16; ++o4) {
      int o = o4 * 4 + o2;
      op[(size_t)o * HH * WW] = S2[px * 65 + o] + bias[o];
    }
  }
}

// ---------------------------------------------------------------------------
extern "C" void kernel_launch(void* const* d_in, const int* in_sizes, int n_in,
                              void* d_out, int out_size, void* d_ws, size_t ws_size,
                              hipStream_t stream) {
  const float* x = (const float*)d_in[0];
  const float* offset = (const float*)d_in[1];
  const float* weight = (const float*)d_in[2];
  const float* bias = (const float*)d_in[3];
  float* out = (float*)d_out;

  // workspace layout
  unsigned short* xt = (unsigned short*)d_ws;                       // 17,305,600 B
  unsigned short* wf = (unsigned short*)((char*)d_ws + 17305600);   //     73,728 B

  k_xpose<<<BB * HH, 256, 0, stream>>>(x, xt);
  k_wfrag<<<144, 256, 0, stream>>>(weight, wf);
  k_deform_main<<<BB * HH * 2, 256, 0, stream>>>(offset, bias, xt, wf, out);
}

// Round 2
// 91.981 us; speedup vs baseline: 1.5232x; 1.5232x over previous
//
#include <hip/hip_runtime.h>
#include <hip/hip_bf16.h>

// Problem constants (from reference)
#define BB 8
#define CC 64
#define OO 64
#define HH 128
#define WW 128
#define HP 130   // padded
#define WP 130
#define KP 9

typedef __attribute__((ext_vector_type(8))) short bf16x8;
typedef __attribute__((ext_vector_type(4))) float f32x4;
typedef __attribute__((ext_vector_type(2))) unsigned u32x2;

static __device__ __forceinline__ unsigned short f2bf(float f) {
  // round-to-nearest-even bf16
  unsigned u = __float_as_uint(f);
  unsigned r = u + 0x7fffu + ((u >> 16) & 1u);
  return (unsigned short)(r >> 16);
}
static __device__ __forceinline__ f32x4 unpk4(u32x2 q) {
  // u32x2 holding 4 bf16 (memory order) -> 4 f32
  f32x4 r;
  r.x = __uint_as_float(q.x << 16);
  r.y = __uint_as_float(q.x & 0xffff0000u);
  r.z = __uint_as_float(q.y << 16);
  r.w = __uint_as_float(q.y & 0xffff0000u);
  return r;
}

// ---------------------------------------------------------------------------
// Kernel 1: x [B][C][H][W] f32  ->  x_t [B][HP][WP][C] bf16, zero borders.
// Zero borders make OOB handling = clamp (pad rows/cols are exactly 0).
// ---------------------------------------------------------------------------
__global__ __launch_bounds__(256) void k_xpose(const float* __restrict__ x,
                                               unsigned short* __restrict__ xt) {
  __shared__ unsigned short tile[128][66];  // [w][c], pad to 66 to avoid bank conflicts
  int wg = blockIdx.x;            // B*H = 1024
  int h = wg & 127, b = wg >> 7;
  int t = threadIdx.x;
  int w = t & 127, chalf = t >> 7;
  const float* xp = x + ((size_t)(b * CC) * HH + h) * WW;  // x[b][0][h][0]
#pragma unroll 4
  for (int c2 = 0; c2 < 32; ++c2) {
    int c = c2 * 2 + chalf;
    float v = xp[(size_t)c * HH * WW + w];
    tile[w][c] = f2bf(v);
  }
  __syncthreads();
  int c = t & 63, w2 = t >> 6;
  unsigned short* xtb = xt + (size_t)b * HP * WP * CC;
#pragma unroll 4
  for (int w4 = 0; w4 < 32; ++w4) {
    int ww = w4 * 4 + w2;
    xtb[((size_t)(h + 1) * WP + (ww + 1)) * CC + c] = tile[ww][c];
  }
  // side borders (x = 0 and x = WP-1) for this row
  if (t < 128) {
    int xx = (t >= 64) ? (WP - 1) : 0;
    xtb[((size_t)(h + 1) * WP + xx) * CC + (t & 63)] = 0;
  }
  // top/bottom zero rows, once per b
  if (h == 0) {
    for (int i = t; i < 2 * WP * CC; i += 256) {
      int top = (i < WP * CC);
      int rem = top ? i : i - WP * CC;
      size_t y = top ? 0 : (HP - 1);
      xtb[y * WP * CC + rem] = 0;
    }
  }
}

// ---------------------------------------------------------------------------
// Kernel 2: weight [O][C][3][3] f32 -> bf16 fragments in MFMA B-operand order.
// flat = (((p*2+ks)*4+nf)*64 + lane)*8 + j ;  c = ks*32+(lane>>4)*8+j ; o = nf*16+(lane&15)
// ---------------------------------------------------------------------------
__global__ __launch_bounds__(256) void k_wfrag(const float* __restrict__ wsrc,
                                               unsigned short* __restrict__ wf) {
  int flat = blockIdx.x * 256 + threadIdx.x;  // < 36864 = 9<<12
  int j = flat & 7;
  int lane = (flat >> 3) & 63;
  int nf = (flat >> 9) & 3;
  int ks = (flat >> 11) & 1;
  int p = flat >> 12;
  int c = ks * 32 + ((lane >> 4) * 8) + j;
  int o = nf * 16 + (lane & 15);
  wf[flat] = f2bf(wsrc[(size_t)(o * CC + c) * KP + p]);
}

// ---------------------------------------------------------------------------
// Main kernel: one wg = (b, h, 64-wide w tile) x all 64 outputs.
// 4 waves; wave w owns pixels [16w, 16w+16). Barrier-free p-loop.
// Lane split for S-build: c4 = lane&15 (channel quad, dwordx2 loads),
// pq = lane>>4 (pixel within quad of 4). 4 iterations cover 16 pixels.
// ---------------------------------------------------------------------------
__global__ __launch_bounds__(256) void k_deform_main(const float* __restrict__ offset,
                                                     const float* __restrict__ bias,
                                                     const unsigned short* __restrict__ xt,
                                                     const unsigned short* __restrict__ wf,
                                                     float* __restrict__ out) {
  __shared__ __align__(16) char lds[17408];
  // layout: [0,9216)  coords: 4 waves * 144 entries * 16B
  //         [9216,17408) S tile: 64 px * 64 c * bf16 (XOR-swizzled rows)
  // epilogue reuses [0,16640) as S2: f32 [64][65]

  int wg = blockIdx.x;                 // 2048
  int tile = wg & 1, h = (wg >> 1) & 127, b = wg >> 8;
  int w0 = tile * 64;
  int t = threadIdx.x, wave = t >> 6, lane = t & 63;

  uint4* coords = reinterpret_cast<uint4*>(lds) + wave * 144;
  char* Sb = lds + 9216;

  // ---- phase 1: vectorized coordinate precompute (144 (p,px) pairs / wave) ----
  // entry: { base_byte_off, wy1_bits, wx1_bits, dx | (dy<<16) }
#pragma unroll
  for (int it = 0; it < 3; ++it) {
    int pair = it * 64 + lane;
    if (pair < 144) {
      int p = pair >> 4, pxl = pair & 15;
      int px = wave * 16 + pxl;
      int w = w0 + px;
      const float* offp = offset + (((size_t)b * 18 + 2 * p) * HH + h) * WW + w;
      float offy = offp[0];
      float offx = offp[HH * WW];
      float cy = (float)(h + p / 3) + offy;   // (h+1) + (p/3 - 1) + offy
      float cx = (float)(w + p % 3) + offx;   // (w+1) + (p%3 - 1) + offx
      float y0f = floorf(cy), x0f = floorf(cx);
      float wy1 = cy - y0f, wx1 = cx - x0f;
      int iy0 = (int)y0f, ix0 = (int)x0f;
      int iy0c = min(max(iy0, 0), HP - 1);
      int iy1c = min(max(iy0 + 1, 0), HP - 1);
      int ix0c = min(max(ix0, 0), WP - 1);
      int ix1c = min(max(ix0 + 1, 0), WP - 1);
      uint4 e;
      e.x = (unsigned)((iy0c * WP + ix0c) * (CC * 2));           // byte offset of corner00
      e.y = __float_as_uint(wy1);
      e.z = __float_as_uint(wx1);
      e.w = (unsigned)((ix1c - ix0c) * (CC * 2)) |
            ((unsigned)((iy1c - iy0c) * (WP * CC * 2)) << 16);   // dx | dy<<16
      coords[pair] = e;  // wave-local; no barrier needed
    }
  }

  f32x4 acc[4];
#pragma unroll
  for (int nf = 0; nf < 4; ++nf) acc[nf] = (f32x4){0.f, 0.f, 0.f, 0.f};

  const char* xb = (const char*)(xt + (size_t)b * HP * WP * CC);
  int c4 = lane & 15, pq = lane >> 4;
  unsigned cb = (unsigned)c4 * 8;               // byte offset of this lane's 4 channels
  char* swave = Sb + wave * 2048 + pq * 128;    // this lane's pixel-row base (it adds it*512)

  for (int p = 0; p < 9; ++p) {
    const uint4* cw = coords + p * 16;
    // ---- build S rows: 4 iterations x (4 pixels in parallel, 4 channels/lane) ----
#pragma unroll
    for (int it = 0; it < 4; ++it) {
      uint4 e = cw[it * 4 + pq];                // 16-lane broadcast ds_read_b128
      unsigned dx = e.w & 0xffffu, dy = e.w >> 16;
      unsigned a00 = e.x + cb;
      u32x2 q00 = *(const u32x2*)(xb + a00);
      u32x2 q01 = *(const u32x2*)(xb + (a00 + dx));
      u32x2 q10 = *(const u32x2*)(xb + (a00 + dy));
      u32x2 q11 = *(const u32x2*)(xb + (a00 + dy + dx));
      float wy1 = __uint_as_float(e.y), wx1 = __uint_as_float(e.z);
      f32x4 v00 = unpk4(q00), v01 = unpk4(q01);
      f32x4 v10 = unpk4(q10), v11 = unpk4(q11);
      f32x4 top = v00 + wx1 * (v01 - v00);
      f32x4 bot = v10 + wx1 * (v11 - v10);
      f32x4 s = top + wy1 * (bot - top);
      unsigned r0, r1;
      asm("v_cvt_pk_bf16_f32 %0, %1, %2" : "=v"(r0) : "v"(s.x), "v"(s.y));
      asm("v_cvt_pk_bf16_f32 %0, %1, %2" : "=v"(r1) : "v"(s.z), "v"(s.w));
      u32x2 pk; pk.x = r0; pk.y = r1;
      // swizzle: row px = wave*16 + it*4 + pq ; (px&7) = (it*4+pq)&7 = (it&1)*4 + pq
      unsigned swz = ((unsigned)(it & 1) * 64) + ((unsigned)pq << 4);
      *reinterpret_cast<u32x2*>(swave + it * 512 + (cb ^ swz)) = pk;
    }
    // ---- MFMA: K-slice of 64 (this p), 2 k-steps ----
#pragma unroll
    for (int ks = 0; ks < 2; ++ks) {
      int px = wave * 16 + (lane & 15);
      int c0b = ks * 64 + ((lane >> 4) * 16);  // byte offset of this lane's k-chunk
      int ba = px * 128 + (c0b ^ ((lane & 7) << 4));  // px&7 == lane&7
      bf16x8 a = *reinterpret_cast<const bf16x8*>(Sb + ba);
      const unsigned short* wfp = wf + (size_t)((p * 2 + ks) * 4) * 64 * 8;
#pragma unroll
      for (int nf = 0; nf < 4; ++nf) {
        bf16x8 bfrag = *reinterpret_cast<const bf16x8*>(wfp + ((nf * 64 + lane) * 8));
        acc[nf] = __builtin_amdgcn_mfma_f32_16x16x32_bf16(a, bfrag, acc[nf], 0, 0, 0);
      }
    }
  }

  // ---- epilogue: LDS transpose for coalesced NCHW stores ----
  __syncthreads();  // everyone done with coords/S before overwrite
  float* S2 = reinterpret_cast<float*>(lds);
#pragma unroll
  for (int nf = 0; nf < 4; ++nf) {
#pragma unroll
    for (int i2 = 0; i2 < 4; ++i2) {
      int px = wave * 16 + ((lane >> 4) * 4) + i2;  // C/D row
      int o = nf * 16 + (lane & 15);                // C/D col
      S2[px * 65 + o] = acc[nf][i2];
    }
  }
  __syncthreads();
  {
    int px = t & 63, o2 = t >> 6;
    float* op = out + (((size_t)b * OO) * HH + h) * WW + w0 + px;
#pragma unroll
    for (int o4 = 0; o4 < 16; ++o4) {
      int o = o4 * 4 + o2;
      op[(size_t)o * HH * WW] = S2[px * 65 + o] + bias[o];
    }
  }
}

// ---------------------------------------------------------------------------
extern "C" void kernel_launch(void* const* d_in, const int* in_sizes, int n_in,
                              void* d_out, int out_size, void* d_ws, size_t ws_size,
                              hipStream_t stream) {
  const float* x = (const float*)d_in[0];
  const float* offset = (const float*)d_in[1];
  const float* weight = (const float*)d_in[2];
  const float* bias = (const float*)d_in[3];
  float* out = (float*)d_out;

  // workspace layout
  unsigned short* xt = (unsigned short*)d_ws;                       // 17,305,600 B
  unsigned short* wf = (unsigned short*)((char*)d_ws + 17305600);   //     73,728 B

  k_xpose<<<BB * HH, 256, 0, stream>>>(x, xt);
  k_wfrag<<<144, 256, 0, stream>>>(weight, wf);
  k_deform_main<<<BB * HH * 2, 256, 0, stream>>>(offset, bias, xt, wf, out);
}

// Round 3
// 74.428 us; speedup vs baseline: 1.8824x; 1.2358x over previous
//
#include <hip/hip_runtime.h>
#include <hip/hip_bf16.h>

// Problem constants (from reference)
#define BB 8
#define CC 64
#define OO 64
#define HH 128
#define WW 128
#define HP 130   // padded
#define WP 130
#define KP 9

typedef __attribute__((ext_vector_type(8))) short bf16x8;
typedef __attribute__((ext_vector_type(4))) float f32x4;
typedef __attribute__((ext_vector_type(2))) unsigned u32x2;

static __device__ __forceinline__ unsigned short f2bf(float f) {
  unsigned u = __float_as_uint(f);
  unsigned r = u + 0x7fffu + ((u >> 16) & 1u);
  return (unsigned short)(r >> 16);
}
static __device__ __forceinline__ f32x4 unpk4(u32x2 q) {
  f32x4 r;
  r.x = __uint_as_float(q.x << 16);
  r.y = __uint_as_float(q.x & 0xffff0000u);
  r.z = __uint_as_float(q.y << 16);
  r.w = __uint_as_float(q.y & 0xffff0000u);
  return r;
}

// ---------------------------------------------------------------------------
// Kernel 1: x [B][C][H][W] f32 -> x_t [B][HP][WP][C] bf16, zero borders.
// XCD-swizzled so XCD k produces x_t[b=k] into its own L2 (main reads it there).
// ---------------------------------------------------------------------------
__global__ __launch_bounds__(256) void k_xpose(const float* __restrict__ x,
                                               unsigned short* __restrict__ xt) {
  __shared__ unsigned short tile[128][66];
  int wg0 = blockIdx.x;           // B*H = 1024, 1024%8==0
  int wg = (wg0 & 7) * 128 + (wg0 >> 3);   // XCD-chunked: XCD k gets b=k
  int h = wg & 127, b = wg >> 7;
  int t = threadIdx.x;
  int w = t & 127, chalf = t >> 7;
  const float* xp = x + ((size_t)(b * CC) * HH + h) * WW;
#pragma unroll 4
  for (int c2 = 0; c2 < 32; ++c2) {
    int c = c2 * 2 + chalf;
    float v = xp[(size_t)c * HH * WW + w];
    tile[w][c] = f2bf(v);
  }
  __syncthreads();
  int c = t & 63, w2 = t >> 6;
  unsigned short* xtb = xt + (size_t)b * HP * WP * CC;
#pragma unroll 4
  for (int w4 = 0; w4 < 32; ++w4) {
    int ww = w4 * 4 + w2;
    xtb[((size_t)(h + 1) * WP + (ww + 1)) * CC + c] = tile[ww][c];
  }
  if (t < 128) {
    int xx = (t >= 64) ? (WP - 1) : 0;
    xtb[((size_t)(h + 1) * WP + xx) * CC + (t & 63)] = 0;
  }
  if (h == 0) {
    for (int i = t; i < 2 * WP * CC; i += 256) {
      int top = (i < WP * CC);
      int rem = top ? i : i - WP * CC;
      size_t y = top ? 0 : (HP - 1);
      xtb[y * WP * CC + rem] = 0;
    }
  }
}

// ---------------------------------------------------------------------------
// Kernel 2: weight -> bf16 MFMA B-fragments (see round-1 comment for layout).
// ---------------------------------------------------------------------------
__global__ __launch_bounds__(256) void k_wfrag(const float* __restrict__ wsrc,
                                               unsigned short* __restrict__ wf) {
  int flat = blockIdx.x * 256 + threadIdx.x;
  int j = flat & 7;
  int lane = (flat >> 3) & 63;
  int nf = (flat >> 9) & 3;
  int ks = (flat >> 11) & 1;
  int p = flat >> 12;
  int c = ks * 32 + ((lane >> 4) * 8) + j;
  int o = nf * 16 + (lane & 15);
  wf[flat] = f2bf(wsrc[(size_t)(o * CC + c) * KP + p]);
}

// ---------------------------------------------------------------------------
// Main kernel: one wg = (b, h, 64-wide w tile) x all 64 outputs. 4 waves,
// wave-local p-loop, software-pipelined: gathers for p+1 in flight across
// MFMA(p). XCD-chunked swizzle keeps x_t[b] resident in one XCD's L2.
// ---------------------------------------------------------------------------
__global__ __launch_bounds__(256) void k_deform_main(const float* __restrict__ offset,
                                                     const float* __restrict__ bias,
                                                     const unsigned short* __restrict__ xt,
                                                     const unsigned short* __restrict__ wf,
                                                     float* __restrict__ out) {
  __shared__ __align__(16) char lds[17408];
  // [0,9216) coords: 4 waves * 144 * 16B ; [9216,17408) S: 64px*64c bf16 swizzled
  int wg0 = blockIdx.x;                  // 2048, 2048%8==0
  int wgs = (wg0 & 7) * 256 + (wg0 >> 3);  // XCD k -> b=k
  int tile = wgs & 1, h = (wgs >> 1) & 127, b = wgs >> 8;
  int w0 = tile * 64;
  int t = threadIdx.x, wave = t >> 6, lane = t & 63;

  uint4* coords = reinterpret_cast<uint4*>(lds) + wave * 144;
  char* Sb = lds + 9216;

  // ---- phase 1: coordinate precompute (144 (p,px) pairs / wave) ----
  // entry: { byte_off(corner00), wy1_bits, wx1_bits, dx | dy<<16 }
#pragma unroll
  for (int it = 0; it < 3; ++it) {
    int pair = it * 64 + lane;
    if (pair < 144) {
      int p = pair >> 4, pxl = pair & 15;
      int px = wave * 16 + pxl;
      int w = w0 + px;
      const float* offp = offset + (((size_t)b * 18 + 2 * p) * HH + h) * WW + w;
      float offy = offp[0];
      float offx = offp[HH * WW];
      float cy = (float)(h + p / 3) + offy;
      float cx = (float)(w + p % 3) + offx;
      float y0f = floorf(cy), x0f = floorf(cx);
      float wy1 = cy - y0f, wx1 = cx - x0f;
      int iy0 = (int)y0f, ix0 = (int)x0f;
      int iy0c = min(max(iy0, 0), HP - 1);
      int iy1c = min(max(iy0 + 1, 0), HP - 1);
      int ix0c = min(max(ix0, 0), WP - 1);
      int ix1c = min(max(ix0 + 1, 0), WP - 1);
      uint4 e;
      e.x = (unsigned)((iy0c * WP + ix0c) * (CC * 2));
      e.y = __float_as_uint(wy1);
      e.z = __float_as_uint(wx1);
      e.w = (unsigned)((ix1c - ix0c) * (CC * 2)) |
            ((unsigned)((iy1c - iy0c) * (WP * CC * 2)) << 16);
      coords[pair] = e;
    }
  }

  f32x4 acc[4];
#pragma unroll
  for (int nf = 0; nf < 4; ++nf) acc[nf] = (f32x4){0.f, 0.f, 0.f, 0.f};

  const char* xb = (const char*)(xt + (size_t)b * HP * WP * CC);
  int c4 = lane & 15, pq = lane >> 4;
  unsigned cb = (unsigned)c4 * 8;
  char* swave = Sb + wave * 2048 + pq * 128;
  const uint4* cwl = coords + pq;  // + p*16 + it*4

  auto LOADC = [&](int p, uint4* eo) {
#pragma unroll
    for (int it = 0; it < 4; ++it) eo[it] = cwl[p * 16 + it * 4];
  };
  auto ISSUE = [&](const uint4* ei, u32x2* go) {
#pragma unroll
    for (int it = 0; it < 4; ++it) {
      unsigned dx = ei[it].w & 0xffffu, dy = ei[it].w >> 16;
      unsigned a00 = ei[it].x + cb;
      go[it * 4 + 0] = *(const u32x2*)(xb + a00);
      go[it * 4 + 1] = *(const u32x2*)(xb + (a00 + dx));
      go[it * 4 + 2] = *(const u32x2*)(xb + (a00 + dy));
      go[it * 4 + 3] = *(const u32x2*)(xb + (a00 + dy + dx));
    }
  };
  auto BUILD = [&](const uint4* ei, const u32x2* gi) {
#pragma unroll
    for (int it = 0; it < 4; ++it) {
      float wy1 = __uint_as_float(ei[it].y), wx1 = __uint_as_float(ei[it].z);
      f32x4 v00 = unpk4(gi[it * 4 + 0]), v01 = unpk4(gi[it * 4 + 1]);
      f32x4 v10 = unpk4(gi[it * 4 + 2]), v11 = unpk4(gi[it * 4 + 3]);
      f32x4 top = v00 + wx1 * (v01 - v00);
      f32x4 bot = v10 + wx1 * (v11 - v10);
      f32x4 s = top + wy1 * (bot - top);
      unsigned r0, r1;
      asm("v_cvt_pk_bf16_f32 %0, %1, %2" : "=v"(r0) : "v"(s.x), "v"(s.y));
      asm("v_cvt_pk_bf16_f32 %0, %1, %2" : "=v"(r1) : "v"(s.z), "v"(s.w));
      u32x2 pk; pk.x = r0; pk.y = r1;
      unsigned swz = ((unsigned)(it & 1) * 64) + ((unsigned)pq << 4);
      *reinterpret_cast<u32x2*>(swave + it * 512 + (cb ^ swz)) = pk;
    }
  };
  auto MFMA = [&](int p) {
    int px = wave * 16 + (lane & 15);
    int c0base = (lane >> 4) * 16;
    const unsigned short* wfp0 = wf + (size_t)p * 4096;
#pragma unroll
    for (int ks = 0; ks < 2; ++ks) {
      int ba = px * 128 + (((ks * 64) + c0base) ^ ((lane & 7) << 4));
      bf16x8 a = *reinterpret_cast<const bf16x8*>(Sb + ba);
      const unsigned short* wfp = wfp0 + ks * 2048;
#pragma unroll
      for (int nf = 0; nf < 4; ++nf) {
        bf16x8 bfrag = *reinterpret_cast<const bf16x8*>(wfp + (nf * 64 + lane) * 8);
        acc[nf] = __builtin_amdgcn_mfma_f32_16x16x32_bf16(a, bfrag, acc[nf], 0, 0, 0);
      }
    }
  };

  // ---- software-pipelined p-loop (wave-local, barrier-free) ----
  uint4 e[4];
  u32x2 g[16];
  LOADC(0, e);
  ISSUE(e, g);
#pragma unroll
  for (int p = 0; p < 9; ++p) {
    uint4 e2[4];
    u32x2 g2[16];
    if (p < 8) LOADC(p + 1, e2);     // ds_reads; latency covered by BUILD
    BUILD(e, g);                     // vmcnt-waits on g (issued last iter)
    if (p < 8) ISSUE(e2, g2);        // gathers in flight across MFMA + next BUILD VALU
    MFMA(p);
    if (p < 8) {
#pragma unroll
      for (int i = 0; i < 4; ++i) e[i] = e2[i];
#pragma unroll
      for (int i = 0; i < 16; ++i) g[i] = g2[i];
    }
  }

  // ---- epilogue: LDS transpose for coalesced NCHW stores ----
  __syncthreads();
  float* S2 = reinterpret_cast<float*>(lds);
#pragma unroll
  for (int nf = 0; nf < 4; ++nf) {
#pragma unroll
    for (int i2 = 0; i2 < 4; ++i2) {
      int px = wave * 16 + ((lane >> 4) * 4) + i2;
      int o = nf * 16 + (lane & 15);
      S2[px * 65 + o] = acc[nf][i2];
    }
  }
  __syncthreads();
  {
    int px = t & 63, o2 = t >> 6;
    float* op = out + (((size_t)b * OO) * HH + h) * WW + w0 + px;
#pragma unroll
    for (int o4 = 0; o4 < 16; ++o4) {
      int o = o4 * 4 + o2;
      op[(size_t)o * HH * WW] = S2[px * 65 + o] + bias[o];
    }
  }
}

// ---------------------------------------------------------------------------
extern "C" void kernel_launch(void* const* d_in, const int* in_sizes, int n_in,
                              void* d_out, int out_size, void* d_ws, size_t ws_size,
                              hipStream_t stream) {
  const float* x = (const float*)d_in[0];
  const float* offset = (const float*)d_in[1];
  const float* weight = (const float*)d_in[2];
  const float* bias = (const float*)d_in[3];
  float* out = (float*)d_out;

  unsigned short* xt = (unsigned short*)d_ws;                       // 17,305,600 B
  unsigned short* wf = (unsigned short*)((char*)d_ws + 17305600);   //     73,728 B

  k_xpose<<<BB * HH, 256, 0, stream>>>(x, xt);
  k_wfrag<<<144, 256, 0, stream>>>(weight, wf);
  k_deform_main<<<BB * HH * 2, 256, 0, stream>>>(offset, bias, xt, wf, out);
}

// Round 4
// 64.304 us; speedup vs baseline: 2.1788x; 1.1574x over previous
//
#include <hip/hip_runtime.h>
#include <hip/hip_bf16.h>

// Problem constants (from reference)
#define BB 8
#define CC 64
#define OO 64
#define HH 128
#define WW 128
#define HP 130   // padded
#define WP 130
#define KP 9

typedef __attribute__((ext_vector_type(8))) short bf16x8;
typedef __attribute__((ext_vector_type(4))) float f32x4;
typedef __attribute__((ext_vector_type(2))) unsigned u32x2;

static __device__ __forceinline__ unsigned short f2bf(float f) {
  unsigned u = __float_as_uint(f);
  unsigned r = u + 0x7fffu + ((u >> 16) & 1u);
  return (unsigned short)(r >> 16);
}
static __device__ __forceinline__ f32x4 unpk4(u32x2 q) {
  f32x4 r;
  r.x = __uint_as_float(q.x << 16);
  r.y = __uint_as_float(q.x & 0xffff0000u);
  r.z = __uint_as_float(q.y << 16);
  r.w = __uint_as_float(q.y & 0xffff0000u);
  return r;
}

// ---------------------------------------------------------------------------
// Kernel 1: x [B][C][H][W] f32 -> x_t [B][HP][WP][C] bf16, zero borders.
// XCD-swizzled so XCD k produces x_t[b=k] into its own L2.
// ---------------------------------------------------------------------------
__global__ __launch_bounds__(256) void k_xpose(const float* __restrict__ x,
                                               unsigned short* __restrict__ xt) {
  __shared__ unsigned short tile[128][66];
  int wg0 = blockIdx.x;           // B*H = 1024
  int wg = (wg0 & 7) * 128 + (wg0 >> 3);   // XCD-chunked: XCD k gets b=k
  int h = wg & 127, b = wg >> 7;
  int t = threadIdx.x;
  int w = t & 127, chalf = t >> 7;
  const float* xp = x + ((size_t)(b * CC) * HH + h) * WW;
#pragma unroll 4
  for (int c2 = 0; c2 < 32; ++c2) {
    int c = c2 * 2 + chalf;
    float v = xp[(size_t)c * HH * WW + w];
    tile[w][c] = f2bf(v);
  }
  __syncthreads();
  int c = t & 63, w2 = t >> 6;
  unsigned short* xtb = xt + (size_t)b * HP * WP * CC;
#pragma unroll 4
  for (int w4 = 0; w4 < 32; ++w4) {
    int ww = w4 * 4 + w2;
    xtb[((size_t)(h + 1) * WP + (ww + 1)) * CC + c] = tile[ww][c];
  }
  if (t < 128) {
    int xx = (t >= 64) ? (WP - 1) : 0;
    xtb[((size_t)(h + 1) * WP + xx) * CC + (t & 63)] = 0;
  }
  if (h == 0) {
    for (int i = t; i < 2 * WP * CC; i += 256) {
      int top = (i < WP * CC);
      int rem = top ? i : i - WP * CC;
      size_t y = top ? 0 : (HP - 1);
      xtb[y * WP * CC + rem] = 0;
    }
  }
}

// ---------------------------------------------------------------------------
// Kernel 2: weight -> bf16 MFMA B-fragments.
// byte(f, lane, j): f = (p*2+ks)*4+nf ; c = ks*32+(lane>>4)*8+j ; o = nf*16+(lane&15)
// ---------------------------------------------------------------------------
__global__ __launch_bounds__(256) void k_wfrag(const float* __restrict__ wsrc,
                                               unsigned short* __restrict__ wf) {
  int flat = blockIdx.x * 256 + threadIdx.x;
  int j = flat & 7;
  int lane = (flat >> 3) & 63;
  int nf = (flat >> 9) & 3;
  int ks = (flat >> 11) & 1;
  int p = flat >> 12;
  int c = ks * 32 + ((lane >> 4) * 8) + j;
  int o = nf * 16 + (lane & 15);
  wf[flat] = f2bf(wsrc[(size_t)(o * CC + c) * KP + p]);
}

// ---------------------------------------------------------------------------
// Main kernel. N-split: wave w computes outputs [16w,16w+16) over ALL 64 px.
// Each wave still BUILDs S for its own 16-px slice; S is block-shared via
// two raw s_barriers per p (gathers for p+1 stay in flight across them).
// ---------------------------------------------------------------------------
__global__ __launch_bounds__(256) void k_deform_main(const float* __restrict__ offset,
                                                     const float* __restrict__ bias,
                                                     const unsigned short* __restrict__ xt,
                                                     const unsigned short* __restrict__ wf,
                                                     float* __restrict__ out) {
  __shared__ __align__(16) char lds[17408];
  // [0,9216) coords: 4 waves * 144 * 16B ; [9216,17408) S: 64px*128B swizzled
  int wg0 = blockIdx.x;                  // 2048
  int wgs = (wg0 & 7) * 256 + (wg0 >> 3);  // XCD k -> b=k
  int tile = wgs & 1, h = (wgs >> 1) & 127, b = wgs >> 8;
  int w0 = tile * 64;
  int t = threadIdx.x, wave = t >> 6, lane = t & 63;

  uint4* coords = reinterpret_cast<uint4*>(lds) + wave * 144;
  char* Sb = lds + 9216;

  // ---- phase 1: coordinate precompute (144 (p,px) pairs / wave) ----
#pragma unroll
  for (int it = 0; it < 3; ++it) {
    int pair = it * 64 + lane;
    if (pair < 144) {
      int p = pair >> 4, pxl = pair & 15;
      int px = wave * 16 + pxl;
      int w = w0 + px;
      const float* offp = offset + (((size_t)b * 18 + 2 * p) * HH + h) * WW + w;
      float offy = offp[0];
      float offx = offp[HH * WW];
      float cy = (float)(h + p / 3) + offy;
      float cx = (float)(w + p % 3) + offx;
      float y0f = floorf(cy), x0f = floorf(cx);
      float wy1 = cy - y0f, wx1 = cx - x0f;
      int iy0 = (int)y0f, ix0 = (int)x0f;
      int iy0c = min(max(iy0, 0), HP - 1);
      int iy1c = min(max(iy0 + 1, 0), HP - 1);
      int ix0c = min(max(ix0, 0), WP - 1);
      int ix1c = min(max(ix0 + 1, 0), WP - 1);
      uint4 e;
      e.x = (unsigned)((iy0c * WP + ix0c) * (CC * 2));
      e.y = __float_as_uint(wy1);
      e.z = __float_as_uint(wx1);
      e.w = (unsigned)((ix1c - ix0c) * (CC * 2)) |
            ((unsigned)((iy1c - iy0c) * (WP * CC * 2)) << 16);
      coords[pair] = e;
    }
  }

  f32x4 acc[4];
#pragma unroll
  for (int m = 0; m < 4; ++m) acc[m] = (f32x4){0.f, 0.f, 0.f, 0.f};

  const char* xb = (const char*)(xt + (size_t)b * HP * WP * CC);
  int c4 = lane & 15, pq = lane >> 4;
  unsigned cb = (unsigned)c4 * 8;
  char* swave = Sb + wave * 2048 + pq * 128;
  const uint4* cwl = coords + pq;  // + p*16 + it*4

  auto LOADC = [&](int p, uint4* eo) {
#pragma unroll
    for (int it = 0; it < 4; ++it) eo[it] = cwl[p * 16 + it * 4];
  };
  auto ISSUE = [&](const uint4* ei, u32x2* go) {
#pragma unroll
    for (int it = 0; it < 4; ++it) {
      unsigned dx = ei[it].w & 0xffffu, dy = ei[it].w >> 16;
      unsigned a00 = ei[it].x + cb;
      go[it * 4 + 0] = *(const u32x2*)(xb + a00);
      go[it * 4 + 1] = *(const u32x2*)(xb + (a00 + dx));
      go[it * 4 + 2] = *(const u32x2*)(xb + (a00 + dy));
      go[it * 4 + 3] = *(const u32x2*)(xb + (a00 + dy + dx));
    }
  };
  auto BUILD = [&](const uint4* ei, const u32x2* gi) {
#pragma unroll
    for (int it = 0; it < 4; ++it) {
      float wy1 = __uint_as_float(ei[it].y), wx1 = __uint_as_float(ei[it].z);
      f32x4 v00 = unpk4(gi[it * 4 + 0]), v01 = unpk4(gi[it * 4 + 1]);
      f32x4 v10 = unpk4(gi[it * 4 + 2]), v11 = unpk4(gi[it * 4 + 3]);
      f32x4 top = v00 + wx1 * (v01 - v00);
      f32x4 bot = v10 + wx1 * (v11 - v10);
      f32x4 s = top + wy1 * (bot - top);
      unsigned r0, r1;
      asm("v_cvt_pk_bf16_f32 %0, %1, %2" : "=v"(r0) : "v"(s.x), "v"(s.y));
      asm("v_cvt_pk_bf16_f32 %0, %1, %2" : "=v"(r1) : "v"(s.z), "v"(s.w));
      u32x2 pk; pk.x = r0; pk.y = r1;
      unsigned swz = ((unsigned)(it & 1) * 64) + ((unsigned)pq << 4);
      *reinterpret_cast<u32x2*>(swave + it * 512 + (cb ^ swz)) = pk;
    }
  };
  auto MFMA = [&](int p) {
    // B-frags for this wave's output slice (nf = wave): 2 x 16B loads
    const char* wfb = (const char*)wf + ((size_t)(p * 8 + wave) * 1024) + (size_t)lane * 16;
    bf16x8 b0 = *reinterpret_cast<const bf16x8*>(wfb);
    bf16x8 b1 = *reinterpret_cast<const bf16x8*>(wfb + 4096);
    int l15 = lane & 15, kc = (lane >> 4) * 16, sw = (lane & 7) << 4;
#pragma unroll
    for (int m = 0; m < 4; ++m) {
      int rb = (m * 16 + l15) * 128;
      bf16x8 a0 = *reinterpret_cast<const bf16x8*>(Sb + rb + (kc ^ sw));
      bf16x8 a1 = *reinterpret_cast<const bf16x8*>(Sb + rb + ((64 + kc) ^ sw));
      acc[m] = __builtin_amdgcn_mfma_f32_16x16x32_bf16(a0, b0, acc[m], 0, 0, 0);
      acc[m] = __builtin_amdgcn_mfma_f32_16x16x32_bf16(a1, b1, acc[m], 0, 0, 0);
    }
  };

  // ---- software-pipelined p-loop ----
  uint4 e[4];
  u32x2 g[16];
  LOADC(0, e);
  ISSUE(e, g);
#pragma unroll
  for (int p = 0; p < 9; ++p) {
    uint4 e2[4];
    u32x2 g2[16];
    if (p < 8) LOADC(p + 1, e2);     // ds_reads; latency covered by BUILD
    BUILD(e, g);                     // consumes gathers, writes S slice
    asm volatile("s_waitcnt lgkmcnt(0)" ::: "memory");  // S writes visible
    __builtin_amdgcn_s_barrier();                        // [bar1]
    if (p < 8) ISSUE(e2, g2);        // p+1 gathers in flight across MFMA+bar2
    MFMA(p);                         // reads all waves' S rows + own wf slice
    asm volatile("s_waitcnt lgkmcnt(0)" ::: "memory");
    __builtin_amdgcn_s_barrier();                        // [bar2] S reusable
    if (p < 8) {
#pragma unroll
      for (int i = 0; i < 4; ++i) e[i] = e2[i];
#pragma unroll
      for (int i = 0; i < 16; ++i) g[i] = g2[i];
    }
  }

  // ---- epilogue: LDS transpose for coalesced NCHW stores ----
  // C/D: col = lane&15 (o within tile), row = (lane>>4)*4 + i2 (px within tile)
  float* S2 = reinterpret_cast<float*>(lds);
#pragma unroll
  for (int m = 0; m < 4; ++m) {
#pragma unroll
    for (int i2 = 0; i2 < 4; ++i2) {
      int px = m * 16 + ((lane >> 4) * 4) + i2;
      int o = wave * 16 + (lane & 15);
      S2[px * 65 + o] = acc[m][i2];
    }
  }
  __syncthreads();
  {
    int px = t & 63, o2 = t >> 6;
    float* op = out + (((size_t)b * OO) * HH + h) * WW + w0 + px;
#pragma unroll
    for (int o4 = 0; o4 < 16; ++o4) {
      int o = o4 * 4 + o2;
      op[(size_t)o * HH * WW] = S2[px * 65 + o] + bias[o];
    }
  }
}

// ---------------------------------------------------------------------------
extern "C" void kernel_launch(void* const* d_in, const int* in_sizes, int n_in,
                              void* d_out, int out_size, void* d_ws, size_t ws_size,
                              hipStream_t stream) {
  const float* x = (const float*)d_in[0];
  const float* offset = (const float*)d_in[1];
  const float* weight = (const float*)d_in[2];
  const float* bias = (const float*)d_in[3];
  float* out = (float*)d_out;

  unsigned short* xt = (unsigned short*)d_ws;                       // 17,305,600 B
  unsigned short* wf = (unsigned short*)((char*)d_ws + 17305600);   //     73,728 B

  k_xpose<<<BB * HH, 256, 0, stream>>>(x, xt);
  k_wfrag<<<144, 256, 0, stream>>>(weight, wf);
  k_deform_main<<<BB * HH * 2, 256, 0, stream>>>(offset, bias, xt, wf, out);
}